// Round 11
// baseline (615.895 us; speedup 1.0000x reference)
//
#include <hip/hip_runtime.h>

#define D 128
#define SCAN_ELEMS 4096   // elements per scan block (256 threads x 16)

typedef __attribute__((ext_vector_type(8))) short short8;
typedef __attribute__((ext_vector_type(4))) float f32x4;

// ---------------- split-bf16 / fp24 helpers ----------------
__device__ inline void f2bf(float f, short& hi, short& lo) {
    union { float f; unsigned u; } a; a.f = f;
    unsigned r = a.u + 0x7fffu + ((a.u >> 16) & 1u);       // RNE to bf16
    hi = (short)(r >> 16);
    union { unsigned u; float f; } h; h.u = ((unsigned)(unsigned short)hi) << 16;
    union { float f; unsigned u; } b; b.f = f - h.f;
    unsigned r2 = b.u + 0x7fffu + ((b.u >> 16) & 1u);
    lo = (short)(r2 >> 16);
}

// fp24 encode: RNE-round fp32 to 24 bits (sign+8exp+15mant)
__device__ inline unsigned enc24(float f) {
    union { float f; unsigned u; } a; a.f = f;
    unsigned r = a.u + 0x7fu + ((a.u >> 8) & 1u);
    return r >> 8;
}

// decode 4 fp24 elems at element-offset off (dual arrays), accumulate
__device__ inline void dec4(const unsigned short* __restrict__ xh,
                            const unsigned char* __restrict__ xl,
                            unsigned off, float* a) {
    uint2 h2 = *reinterpret_cast<const uint2*>(xh + off);
    unsigned lb = *reinterpret_cast<const unsigned*>(xl + off);
    union { unsigned u; float f; } v0, v1, v2, v3;
    v0.u = ((h2.x & 0xffffu) << 16) | ((lb & 0xffu) << 8);
    v1.u = (h2.x & 0xffff0000u)     | (((lb >> 8) & 0xffu) << 8);
    v2.u = ((h2.y & 0xffffu) << 16) | (((lb >> 16) & 0xffu) << 8);
    v3.u = (h2.y & 0xffff0000u)     | ((lb >> 24) << 8);
    a[0] += v0.f; a[1] += v1.f; a[2] += v2.f; a[3] += v3.f;
}

// ---------------- precompute: count (+fused wsplit) ----------------
// deg[] counts REAL edges only (self-loop handled as +1 at use sites).

__device__ void wsplit_body(int tid, const float* __restrict__ W1,
                            const float* __restrict__ W2, const float* __restrict__ W3,
                            short* __restrict__ Bsw) {
    int layer = tid >> 14;
    int rem = tid & 16383;
    int k = rem >> 7, c = rem & 127;
    const float* Wg = (layer == 0) ? W1 : ((layer == 1) ? W2 : W3);
    float v = Wg[k * 128 + c];
    short hi, lo; f2bf(v, hi, lo);
    int ktile = k >> 5, kk = k & 31, q = kk >> 3, j = kk & 7;
    int ct = c >> 4, mm = c & 15, lane = q * 16 + mm;
    int idx = layer * 32768 + ((ktile * 8 + ct) * 64 + lane) * 8 + j;
    Bsw[idx] = hi;
    Bsw[idx + 16384] = lo;
}

__global__ __launch_bounds__(256) void count_wsplit_kernel(const int* __restrict__ dst,
                                                           int* __restrict__ deg,
                                                           int* __restrict__ rank, int e,
                                                           int nbCount,
                                                           const float* __restrict__ W1,
                                                           const float* __restrict__ W2,
                                                           const float* __restrict__ W3,
                                                           short* __restrict__ Bsw) {
    if ((int)blockIdx.x < nbCount) {
        int i = blockIdx.x * 256 + threadIdx.x;
        if (i < e) rank[i] = atomicAdd(&deg[dst[i]], 1);
    } else {
        int tid = (blockIdx.x - nbCount) * 256 + threadIdx.x;
        wsplit_body(tid, W1, W2, W3, Bsw);
    }
}

// ---- hierarchical scan ----
__global__ __launch_bounds__(256) void scanA_kernel(const int* __restrict__ deg,
                                                    int* __restrict__ blkSums, int n) {
    __shared__ int waveSums[4];
    int t = threadIdx.x;
    int base = blockIdx.x * SCAN_ELEMS + t * 16;
    int s = 0;
    if (base + 16 <= n) {
        const int4* p = reinterpret_cast<const int4*>(deg + base);
        #pragma unroll
        for (int k = 0; k < 4; ++k) {
            int4 v = p[k];
            s += v.x + v.y + v.z + v.w;
        }
    } else {
        for (int k = 0; k < 16; ++k) {
            int i = base + k;
            if (i < n) s += deg[i];
        }
    }
    #pragma unroll
    for (int off = 32; off > 0; off >>= 1) s += __shfl_down(s, off);
    int lane = t & 63, w = t >> 6;
    if (lane == 0) waveSums[w] = s;
    __syncthreads();
    if (t == 0) blkSums[blockIdx.x] = waveSums[0] + waveSums[1] + waveSums[2] + waveSums[3];
}

__global__ __launch_bounds__(256) void scanC_kernel(const int* __restrict__ deg,
                                                    const int* __restrict__ blkSums,
                                                    int* __restrict__ offsets,
                                                    float* __restrict__ dinv, int n, int nblk) {
    __shared__ int waveSums[4];
    __shared__ int blkBase;
    int t = threadIdx.x;
    int lane = t & 63, w = t >> 6;

    if (t < 64) {
        int s = (t < nblk && t < (int)blockIdx.x) ? blkSums[t] : 0;
        #pragma unroll
        for (int off = 32; off > 0; off >>= 1) s += __shfl_down(s, off);
        if (t == 0) blkBase = s;
    }

    int base = blockIdx.x * SCAN_ELEMS + t * 16;
    int v[16];
    int s = 0;
    #pragma unroll
    for (int k = 0; k < 16; ++k) {
        int i = base + k;
        int d = (i < n) ? deg[i] : 0;
        v[k] = d;
        s += d;
    }
    int incl = s;
    #pragma unroll
    for (int off = 1; off < 64; off <<= 1) {
        int u = __shfl_up(incl, off);
        if (lane >= off) incl += u;
    }
    if (lane == 63) waveSums[w] = incl;
    __syncthreads();
    int waveOff = 0;
    for (int i = 0; i < 4; ++i) if (i < w) waveOff += waveSums[i];
    int off0 = blkBase + waveOff + incl - s;

    #pragma unroll
    for (int k = 0; k < 16; ++k) {
        int i = base + k;
        if (i < n) {
            offsets[i] = off0;
            dinv[i] = rsqrtf((float)(v[k] + 1));   // +1 self-loop
            off0 += v[k];
        }
    }
}

// ---------------- split-bf16 MFMA GEMM body (no LDS, slice-major fp24 out) ----------------
// xh/xl laid out [8 slices][n][16]; slice of col = ct (col = ct*16 + m).
__device__ void gemm_body(int blk, const float* __restrict__ A,
                          const short* __restrict__ Bsw,
                          const float* __restrict__ dinv,
                          unsigned short* __restrict__ xh,
                          unsigned char* __restrict__ xl, int n, int t) {
    int w = t >> 6;
    int lane = t & 63;
    int quad = lane >> 4;
    int m = lane & 15;

    int rowBase = blk * 64 + w * 16;
    int arow = rowBase + m;
    bool valid = arow < n;
    const float* ap = A + (size_t)(valid ? arow : 0) * D + quad * 8;

    f32x4 acc[8];
    #pragma unroll
    for (int ct = 0; ct < 8; ++ct) acc[ct] = (f32x4){0.f, 0.f, 0.f, 0.f};

    #pragma unroll
    for (int kt = 0; kt < 4; ++kt) {
        short8 a_hi, a_lo;
        {
            float4 f0 = *reinterpret_cast<const float4*>(ap + kt * 32);
            float4 f1 = *reinterpret_cast<const float4*>(ap + kt * 32 + 4);
            float fv[8] = {f0.x, f0.y, f0.z, f0.w, f1.x, f1.y, f1.z, f1.w};
            #pragma unroll
            for (int j = 0; j < 8; ++j) {
                short h, l; f2bf(valid ? fv[j] : 0.f, h, l);
                a_hi[j] = h; a_lo[j] = l;
            }
        }
        const short* bp = Bsw + (kt * 512 + lane) * 8;
        #pragma unroll
        for (int ct = 0; ct < 8; ++ct) {
            short8 b_hi = *reinterpret_cast<const short8*>(bp + ct * 512);
            short8 b_lo = *reinterpret_cast<const short8*>(bp + 16384 + ct * 512);
            acc[ct] = __builtin_amdgcn_mfma_f32_16x16x32_bf16(a_hi, b_hi, acc[ct], 0, 0, 0);
            acc[ct] = __builtin_amdgcn_mfma_f32_16x16x32_bf16(a_hi, b_lo, acc[ct], 0, 0, 0);
            acc[ct] = __builtin_amdgcn_mfma_f32_16x16x32_bf16(a_lo, b_hi, acc[ct], 0, 0, 0);
        }
    }

    // epilogue: C/D layout col=lane&15, row=quad*4+reg; slice = ct.
    #pragma unroll
    for (int r = 0; r < 4; ++r) {
        int row = rowBase + quad * 4 + r;
        if (row < n) {
            float s = dinv[row];
            #pragma unroll
            for (int ct = 0; ct < 8; ++ct) {
                unsigned e24 = enc24(acc[ct][r] * s);
                unsigned off = ((unsigned)ct * (unsigned)n + (unsigned)row) * 16u + (unsigned)m;
                xh[off] = (unsigned short)(e24 >> 8);
                xl[off] = (unsigned char)(e24 & 0xffu);
            }
        }
    }
}

__global__ __launch_bounds__(256) void gemm_kernel(const float* __restrict__ A,
                                                   const short* __restrict__ Bsw,
                                                   const float* __restrict__ dinv,
                                                   unsigned short* __restrict__ xh,
                                                   unsigned char* __restrict__ xl, int n) {
    gemm_body(blockIdx.x, A, Bsw, dinv, xh, xl, n, threadIdx.x);
}

// fill fused with layer-1 gemm (independent work, one dispatch)
__global__ __launch_bounds__(256) void fill_gemm_kernel(const int* __restrict__ src,
                                                        const int* __restrict__ dst,
                                                        const int* __restrict__ offsets,
                                                        const int* __restrict__ rank,
                                                        int* __restrict__ csr_src, int e,
                                                        int nbFill,
                                                        const float* __restrict__ A,
                                                        const short* __restrict__ Bsw,
                                                        const float* __restrict__ dinv,
                                                        unsigned short* __restrict__ xh,
                                                        unsigned char* __restrict__ xl, int n) {
    if ((int)blockIdx.x < nbFill) {
        int i = blockIdx.x * 256 + threadIdx.x;
        if (i < e) csr_src[offsets[dst[i]] + rank[i]] = src[i];
    } else {
        gemm_body(blockIdx.x - nbFill, A, Bsw, dinv, xh, xl, n, threadIdx.x);
    }
}

// ---------------- sliced aggregation (layers 1,2) ----------------
// Block b: slice = b&7 (XCD-pinned by %8 round-robin), 4 nodes (1/wave).
// Lane: e16 = lane&15 (edge subgroup), g = lane>>4 (4 cols each).
//   h[d][cols] = relu( dinv[d]*(sum_e xws[s][cols] + xws[d][cols]) + b[cols] )
__global__ __launch_bounds__(256) void aggs_kernel(const unsigned short* __restrict__ xh,
                                                   const unsigned char* __restrict__ xl,
                                                   const int* __restrict__ csr_src,
                                                   const int* __restrict__ offsets,
                                                   const int* __restrict__ deg,
                                                   const float* __restrict__ dinv,
                                                   const float* __restrict__ bias,
                                                   float* __restrict__ outp, int n) {
    int b = blockIdx.x;
    int slice = b & 7;
    int w = threadIdx.x >> 6;
    int node = (b >> 3) * 4 + w;
    if (node >= n) return;
    int lane = threadIdx.x & 63;
    int e16 = lane & 15;
    int g = lane >> 4;

    unsigned sbase = (unsigned)slice * (unsigned)n;
    unsigned g4 = (unsigned)(g << 2);

    int base = offsets[node];
    int cnt  = deg[node];
    float di = dinv[node];

    float vs[4] = {};
    dec4(xh, xl, (sbase + (unsigned)node) * 16u + g4, vs);
    float4 bb = *reinterpret_cast<const float4*>(bias + slice * 16 + (g << 2));

    float a[4] = {};
    if (cnt <= 64) {
        int idx = (lane < cnt) ? csr_src[base + lane] : 0;
        for (int j = 0; j < cnt; j += 16) {
            int eI = j + e16;
            int s0 = __shfl(idx, eI);
            if (eI < cnt)
                dec4(xh, xl, (sbase + (unsigned)s0) * 16u + g4, a);
        }
    } else {
        for (int j = 0; j < cnt; j += 16) {
            int eI = j + e16;
            if (eI < cnt) {
                int s0 = csr_src[base + eI];
                dec4(xh, xl, (sbase + (unsigned)s0) * 16u + g4, a);
            }
        }
    }

    // reduce over the 16 edge lanes (within each 16-lane group)
    #pragma unroll
    for (int s = 1; s < 16; s <<= 1) {
        #pragma unroll
        for (int k = 0; k < 4; ++k) a[k] += __shfl_down(a[k], s);
    }

    if (e16 == 0) {
        float4 r;
        r.x = fmaxf(di * (a[0] + vs[0]) + bb.x, 0.f);
        r.y = fmaxf(di * (a[1] + vs[1]) + bb.y, 0.f);
        r.z = fmaxf(di * (a[2] + vs[2]) + bb.z, 0.f);
        r.w = fmaxf(di * (a[3] + vs[3]) + bb.w, 0.f);
        *reinterpret_cast<float4*>(outp + (size_t)node * D + slice * 16 + (g << 2)) = r;
    }
}

// ---------------- full-row aggregation + fused fc head (layer 3) ----------------
// Half-wave per row (round-10 structure); loads adapted to slice-major layout:
// l32 -> s = l32>>2, cp = (l32&3)*4, col = s*16+cp.
__global__ __launch_bounds__(256) void aggf_kernel(const unsigned short* __restrict__ xh,
                                                   const unsigned char* __restrict__ xl,
                                                   const int* __restrict__ csr_src,
                                                   const int* __restrict__ offsets,
                                                   const int* __restrict__ deg,
                                                   const float* __restrict__ dinv,
                                                   const float* __restrict__ bias,
                                                   const float* __restrict__ fcw,
                                                   const float* __restrict__ fcb,
                                                   float* __restrict__ fcout, int n) {
    int wave = (blockIdx.x * blockDim.x + threadIdx.x) >> 6;
    int lane = threadIdx.x & 63;
    if (wave >= n) return;
    int node = wave;
    int half = lane >> 5;
    int l32  = lane & 31;
    unsigned srow = (unsigned)(l32 >> 2);          // slice 0..7
    unsigned cp   = (unsigned)((l32 & 3) << 2);    // 0,4,8,12
    int colb = (int)(srow * 16 + cp);
    unsigned sb = srow * (unsigned)n;

    int base = offsets[node];
    int cnt  = deg[node];
    float di = dinv[node];

    float vs[4] = {};
    dec4(xh, xl, (sb + (unsigned)node) * 16u + cp, vs);
    float4 bb = *reinterpret_cast<const float4*>(bias + colb);

    float a0[4] = {}, a1[4] = {}, a2[4] = {}, a3[4] = {};

    if (cnt <= 64) {
        int idx = (lane < cnt) ? csr_src[base + lane] : 0;
        int j = 0;
        for (; j + 8 <= cnt; j += 8) {
            int s0 = __shfl(idx, j     + half);
            int s1 = __shfl(idx, j + 2 + half);
            int s2 = __shfl(idx, j + 4 + half);
            int s3 = __shfl(idx, j + 6 + half);
            dec4(xh, xl, (sb + (unsigned)s0) * 16u + cp, a0);
            dec4(xh, xl, (sb + (unsigned)s1) * 16u + cp, a1);
            dec4(xh, xl, (sb + (unsigned)s2) * 16u + cp, a2);
            dec4(xh, xl, (sb + (unsigned)s3) * 16u + cp, a3);
        }
        for (; j + 2 <= cnt; j += 2) {
            int s0 = __shfl(idx, j + half);
            dec4(xh, xl, (sb + (unsigned)s0) * 16u + cp, a0);
        }
        if (j < cnt) {
            int s0 = __shfl(idx, j);
            if (half == 0) dec4(xh, xl, (sb + (unsigned)s0) * 16u + cp, a1);
        }
    } else {
        int j = 0;
        for (; j + 2 <= cnt; j += 2) {
            int s = csr_src[base + j + half];
            dec4(xh, xl, (sb + (unsigned)s) * 16u + cp, a0);
        }
        if (j < cnt && half == 0) {
            int s = csr_src[base + j];
            dec4(xh, xl, (sb + (unsigned)s) * 16u + cp, a1);
        }
    }

    #pragma unroll
    for (int k = 0; k < 4; ++k) {
        a0[k] += a1[k] + a2[k] + a3[k];
        a0[k] += __shfl_down(a0[k], 32);
    }

    float4 wv = *reinterpret_cast<const float4*>(fcw + colb);
    float s = 0.f;
    if (half == 0) {
        float r0 = fmaxf(di * (a0[0] + vs[0]) + bb.x, 0.f);
        float r1 = fmaxf(di * (a0[1] + vs[1]) + bb.y, 0.f);
        float r2 = fmaxf(di * (a0[2] + vs[2]) + bb.z, 0.f);
        float r3 = fmaxf(di * (a0[3] + vs[3]) + bb.w, 0.f);
        s = r0 * wv.x + r1 * wv.y + r2 * wv.z + r3 * wv.w;
    }
    #pragma unroll
    for (int off = 32; off > 0; off >>= 1) s += __shfl_down(s, off);
    if (lane == 0) fcout[node] = s + fcb[0];
}

// ---------------- launch ----------------

extern "C" void kernel_launch(void* const* d_in, const int* in_sizes, int n_in,
                              void* d_out, int out_size, void* d_ws, size_t ws_size,
                              hipStream_t stream) {
    const float* x   = (const float*)d_in[0];
    const int*   ei  = (const int*)d_in[1];
    const float* W1  = (const float*)d_in[2];
    const float* b1  = (const float*)d_in[3];
    const float* W2  = (const float*)d_in[4];
    const float* b2  = (const float*)d_in[5];
    const float* W3  = (const float*)d_in[6];
    const float* b3  = (const float*)d_in[7];
    const float* Wfc = (const float*)d_in[8];
    const float* bfc = (const float*)d_in[9];
    float* outp = (float*)d_out;

    const int n = in_sizes[0] / D;        // 50000
    const int e = in_sizes[1] / 2;        // 800000
    const int* src = ei;
    const int* dst = ei + e;

    char* ws = (char*)d_ws;
    size_t off = 0;
    auto alloc = [&](size_t bytes) {
        void* p = ws + off;
        off += (bytes + 255) & ~(size_t)255;
        return p;
    };
    int*            deg     = (int*)alloc((size_t)n * 4);
    size_t          zero_bytes = off;     // deg zeroed
    int*            offsets = (int*)alloc((size_t)n * 4);
    float*          dinv    = (float*)alloc((size_t)n * 4);
    int*            blkSums = (int*)alloc(64 * 4);
    short*          Bsw     = (short*)alloc((size_t)3 * 32768 * 2);
    int*            rank    = (int*)alloc((size_t)e * 4);
    int*            csr_src = (int*)alloc((size_t)e * 4);
    unsigned short* xhbuf   = (unsigned short*)alloc((size_t)n * 128 * 2);  // fp24 hi16 [8][n][16]
    unsigned char*  xlbuf   = (unsigned char*)alloc((size_t)n * 128);       // fp24 lo8  [8][n][16]
    float*          buf1    = (float*)alloc((size_t)n * D * 4);             // fp32 h

    int eb256 = (e + 255) / 256;                           // 3125
    int scan_blocks = (n + SCAN_ELEMS - 1) / SCAN_ELEMS;   // 13 (<=64)
    int gemm_blocks = (n + 63) / 64;                       // 782
    int aggs_blocks = ((n + 3) / 4) * 8;                   // 100000
    int aggf_blocks = (n + 3) / 4;                         // 12500

    hipMemsetAsync(ws, 0, zero_bytes, stream);
    count_wsplit_kernel<<<eb256 + 192, 256, 0, stream>>>(dst, deg, rank, e, eb256,
                                                         W1, W2, W3, Bsw);
    scanA_kernel<<<scan_blocks, 256, 0, stream>>>(deg, blkSums, n);
    scanC_kernel<<<scan_blocks, 256, 0, stream>>>(deg, blkSums, offsets, dinv, n, scan_blocks);
    fill_gemm_kernel<<<eb256 + gemm_blocks, 256, 0, stream>>>(src, dst, offsets, rank, csr_src,
                                                              e, eb256, x, Bsw, dinv,
                                                              xhbuf, xlbuf, n);
    aggs_kernel<<<aggs_blocks, 256, 0, stream>>>(xhbuf, xlbuf, csr_src, offsets, deg, dinv,
                                                 b1, buf1, n);
    gemm_kernel<<<gemm_blocks, 256, 0, stream>>>(buf1, Bsw + 32768, dinv, xhbuf, xlbuf, n);
    aggs_kernel<<<aggs_blocks, 256, 0, stream>>>(xhbuf, xlbuf, csr_src, offsets, deg, dinv,
                                                 b2, buf1, n);
    gemm_kernel<<<gemm_blocks, 256, 0, stream>>>(buf1, Bsw + 65536, dinv, xhbuf, xlbuf, n);
    aggf_kernel<<<aggf_blocks, 256, 0, stream>>>(xhbuf, xlbuf, csr_src, offsets, deg, dinv,
                                                 b3, Wfc, bfc, outp, n);
}

// Round 12
// 336.087 us; speedup vs baseline: 1.8325x; 1.8325x over previous
//
#include <hip/hip_runtime.h>

#define D 128
#define SCAN_ELEMS 4096   // elements per scan block (256 threads x 16)

typedef __attribute__((ext_vector_type(8))) short short8;
typedef __attribute__((ext_vector_type(4))) float f32x4;

// ---------------- split-bf16 / fp24 helpers ----------------
__device__ inline void f2bf(float f, short& hi, short& lo) {
    union { float f; unsigned u; } a; a.f = f;
    unsigned r = a.u + 0x7fffu + ((a.u >> 16) & 1u);       // RNE to bf16
    hi = (short)(r >> 16);
    union { unsigned u; float f; } h; h.u = ((unsigned)(unsigned short)hi) << 16;
    union { float f; unsigned u; } b; b.f = f - h.f;
    unsigned r2 = b.u + 0x7fffu + ((b.u >> 16) & 1u);
    lo = (short)(r2 >> 16);
}

// fp24 encode: RNE-round fp32 to 24 bits (sign+8exp+15mant)
__device__ inline unsigned enc24(float f) {
    union { float f; unsigned u; } a; a.f = f;
    unsigned r = a.u + 0x7fu + ((a.u >> 8) & 1u);
    return r >> 8;
}

// decode 4 fp24 elems (row-major dual arrays) at row,col; accumulate.
// masks arranged for v_and_or_b32 fusion.
__device__ inline void g24(const unsigned short* __restrict__ xh,
                           const unsigned char* __restrict__ xl,
                           int row, int c, float4& a) {
    uint2 h2 = *reinterpret_cast<const uint2*>(xh + (size_t)row * 128 + c);
    unsigned lb = *reinterpret_cast<const unsigned*>(xl + (size_t)row * 128 + c);
    union { unsigned u; float f; } v0, v1, v2, v3;
    v0.u = (h2.x << 16)          | ((lb << 8) & 0xff00u);
    v1.u = (h2.x & 0xffff0000u)  | (lb & 0xff00u);
    v2.u = (h2.y << 16)          | ((lb >> 8) & 0xff00u);
    v3.u = (h2.y & 0xffff0000u)  | ((lb >> 16) & 0xff00u);
    a.x += v0.f; a.y += v1.f; a.z += v2.f; a.w += v3.f;
}

// ---------------- precompute: count (+fused wsplit) ----------------
// deg[] counts REAL edges only (self-loop handled as +1 at use sites).

__device__ void wsplit_body(int tid, const float* __restrict__ W1,
                            const float* __restrict__ W2, const float* __restrict__ W3,
                            short* __restrict__ Bsw) {
    int layer = tid >> 14;
    int rem = tid & 16383;
    int k = rem >> 7, c = rem & 127;
    const float* Wg = (layer == 0) ? W1 : ((layer == 1) ? W2 : W3);
    float v = Wg[k * 128 + c];
    short hi, lo; f2bf(v, hi, lo);
    int ktile = k >> 5, kk = k & 31, q = kk >> 3, j = kk & 7;
    int ct = c >> 4, mm = c & 15, lane = q * 16 + mm;
    int idx = layer * 32768 + ((ktile * 8 + ct) * 64 + lane) * 8 + j;
    Bsw[idx] = hi;
    Bsw[idx + 16384] = lo;
}

__global__ __launch_bounds__(256) void count_wsplit_kernel(const int* __restrict__ dst,
                                                           int* __restrict__ deg,
                                                           unsigned short* __restrict__ rank,
                                                           int e, int nbCount,
                                                           const float* __restrict__ W1,
                                                           const float* __restrict__ W2,
                                                           const float* __restrict__ W3,
                                                           short* __restrict__ Bsw) {
    if ((int)blockIdx.x < nbCount) {
        int i = blockIdx.x * 256 + threadIdx.x;
        if (i < e) rank[i] = (unsigned short)atomicAdd(&deg[dst[i]], 1);
    } else {
        int tid = (blockIdx.x - nbCount) * 256 + threadIdx.x;
        wsplit_body(tid, W1, W2, W3, Bsw);
    }
}

// ---- hierarchical scan ----
__global__ __launch_bounds__(256) void scanA_kernel(const int* __restrict__ deg,
                                                    int* __restrict__ blkSums, int n) {
    __shared__ int waveSums[4];
    int t = threadIdx.x;
    int base = blockIdx.x * SCAN_ELEMS + t * 16;
    int s = 0;
    if (base + 16 <= n) {
        const int4* p = reinterpret_cast<const int4*>(deg + base);
        #pragma unroll
        for (int k = 0; k < 4; ++k) {
            int4 v = p[k];
            s += v.x + v.y + v.z + v.w;
        }
    } else {
        for (int k = 0; k < 16; ++k) {
            int i = base + k;
            if (i < n) s += deg[i];
        }
    }
    #pragma unroll
    for (int off = 32; off > 0; off >>= 1) s += __shfl_down(s, off);
    int lane = t & 63, w = t >> 6;
    if (lane == 0) waveSums[w] = s;
    __syncthreads();
    if (t == 0) blkSums[blockIdx.x] = waveSums[0] + waveSums[1] + waveSums[2] + waveSums[3];
}

__global__ __launch_bounds__(256) void scanC_kernel(const int* __restrict__ deg,
                                                    const int* __restrict__ blkSums,
                                                    int* __restrict__ offsets,
                                                    float* __restrict__ dinv, int n, int nblk) {
    __shared__ int waveSums[4];
    __shared__ int blkBase;
    int t = threadIdx.x;
    int lane = t & 63, w = t >> 6;

    if (t < 64) {
        int s = (t < nblk && t < (int)blockIdx.x) ? blkSums[t] : 0;
        #pragma unroll
        for (int off = 32; off > 0; off >>= 1) s += __shfl_down(s, off);
        if (t == 0) blkBase = s;
    }

    int base = blockIdx.x * SCAN_ELEMS + t * 16;
    int v[16];
    int s = 0;
    #pragma unroll
    for (int k = 0; k < 16; ++k) {
        int i = base + k;
        int d = (i < n) ? deg[i] : 0;
        v[k] = d;
        s += d;
    }
    int incl = s;
    #pragma unroll
    for (int off = 1; off < 64; off <<= 1) {
        int u = __shfl_up(incl, off);
        if (lane >= off) incl += u;
    }
    if (lane == 63) waveSums[w] = incl;
    __syncthreads();
    int waveOff = 0;
    for (int i = 0; i < 4; ++i) if (i < w) waveOff += waveSums[i];
    int off0 = blkBase + waveOff + incl - s;

    #pragma unroll
    for (int k = 0; k < 16; ++k) {
        int i = base + k;
        if (i < n) {
            offsets[i] = off0;
            dinv[i] = rsqrtf((float)(v[k] + 1));   // +1 self-loop
            off0 += v[k];
        }
    }
}

// ---------------- split-bf16 MFMA GEMM body (no LDS, row-major fp24 dual out) ----------------
__device__ void gemm_body(int blk, const float* __restrict__ A,
                          const short* __restrict__ Bsw,
                          const float* __restrict__ dinv,
                          unsigned short* __restrict__ xh,
                          unsigned char* __restrict__ xl, int n, int t) {
    int w = t >> 6;
    int lane = t & 63;
    int quad = lane >> 4;
    int m = lane & 15;

    int rowBase = blk * 64 + w * 16;
    int arow = rowBase + m;
    bool valid = arow < n;
    const float* ap = A + (size_t)(valid ? arow : 0) * D + quad * 8;

    f32x4 acc[8];
    #pragma unroll
    for (int ct = 0; ct < 8; ++ct) acc[ct] = (f32x4){0.f, 0.f, 0.f, 0.f};

    #pragma unroll
    for (int kt = 0; kt < 4; ++kt) {
        short8 a_hi, a_lo;
        {
            float4 f0 = *reinterpret_cast<const float4*>(ap + kt * 32);
            float4 f1 = *reinterpret_cast<const float4*>(ap + kt * 32 + 4);
            float fv[8] = {f0.x, f0.y, f0.z, f0.w, f1.x, f1.y, f1.z, f1.w};
            #pragma unroll
            for (int j = 0; j < 8; ++j) {
                short h, l; f2bf(valid ? fv[j] : 0.f, h, l);
                a_hi[j] = h; a_lo[j] = l;
            }
        }
        const short* bp = Bsw + (kt * 512 + lane) * 8;
        #pragma unroll
        for (int ct = 0; ct < 8; ++ct) {
            short8 b_hi = *reinterpret_cast<const short8*>(bp + ct * 512);
            short8 b_lo = *reinterpret_cast<const short8*>(bp + 16384 + ct * 512);
            acc[ct] = __builtin_amdgcn_mfma_f32_16x16x32_bf16(a_hi, b_hi, acc[ct], 0, 0, 0);
            acc[ct] = __builtin_amdgcn_mfma_f32_16x16x32_bf16(a_hi, b_lo, acc[ct], 0, 0, 0);
            acc[ct] = __builtin_amdgcn_mfma_f32_16x16x32_bf16(a_lo, b_hi, acc[ct], 0, 0, 0);
        }
    }

    // epilogue: C/D layout col=lane&15, row=quad*4+reg; row-major dual store
    #pragma unroll
    for (int r = 0; r < 4; ++r) {
        int row = rowBase + quad * 4 + r;
        if (row < n) {
            float s = dinv[row];
            size_t rb = (size_t)row * 128 + m;
            #pragma unroll
            for (int ct = 0; ct < 8; ++ct) {
                unsigned e24 = enc24(acc[ct][r] * s);
                xh[rb + ct * 16] = (unsigned short)(e24 >> 8);
                xl[rb + ct * 16] = (unsigned char)(e24 & 0xffu);
            }
        }
    }
}

__global__ __launch_bounds__(256) void gemm_kernel(const float* __restrict__ A,
                                                   const short* __restrict__ Bsw,
                                                   const float* __restrict__ dinv,
                                                   unsigned short* __restrict__ xh,
                                                   unsigned char* __restrict__ xl, int n) {
    gemm_body(blockIdx.x, A, Bsw, dinv, xh, xl, n, threadIdx.x);
}

// fill fused with layer-1 gemm (independent work, one dispatch)
__global__ __launch_bounds__(256) void fill_gemm_kernel(const int* __restrict__ src,
                                                        const int* __restrict__ dst,
                                                        const int* __restrict__ offsets,
                                                        const unsigned short* __restrict__ rank,
                                                        unsigned short* __restrict__ csr_src,
                                                        int e, int nbFill,
                                                        const float* __restrict__ A,
                                                        const short* __restrict__ Bsw,
                                                        const float* __restrict__ dinv,
                                                        unsigned short* __restrict__ xh,
                                                        unsigned char* __restrict__ xl, int n) {
    if ((int)blockIdx.x < nbFill) {
        int i = blockIdx.x * 256 + threadIdx.x;
        if (i < e) csr_src[offsets[dst[i]] + rank[i]] = (unsigned short)src[i];
    } else {
        gemm_body(blockIdx.x - nbFill, A, Bsw, dinv, xh, xl, n, threadIdx.x);
    }
}

// ---------------- aggregation (+ optional fused fc head) ----------------
// xws rows fp24 dual-array row-major, pre-scaled by dinv[row]:
//   h[d] = relu( dinv[d] * (sum_{e:s->d} xws[s] + xws[d]) + b )
__global__ __launch_bounds__(256) void agg_kernel(const unsigned short* __restrict__ xh,
                                                  const unsigned char* __restrict__ xl,
                                                  const unsigned short* __restrict__ csr_src,
                                                  const int* __restrict__ offsets,
                                                  const int* __restrict__ deg,
                                                  const float* __restrict__ dinv,
                                                  const float* __restrict__ bias,
                                                  float* __restrict__ outp,
                                                  const float* __restrict__ fcw,
                                                  const float* __restrict__ fcb,
                                                  float* __restrict__ fcout,
                                                  int n) {
    int wave = (blockIdx.x * blockDim.x + threadIdx.x) >> 6;
    int lane = threadIdx.x & 63;
    if (wave >= n) return;
    int node = wave;
    int half = lane >> 5;
    int l32  = lane & 31;
    int col  = l32 << 2;

    int base = offsets[node];
    int cnt  = deg[node];

    float di = dinv[node];
    float4 vs = make_float4(0.f, 0.f, 0.f, 0.f);
    g24(xh, xl, node, col, vs);
    float4 b = *reinterpret_cast<const float4*>(bias + col);

    float4 acc0 = make_float4(0.f, 0.f, 0.f, 0.f);
    float4 acc1 = make_float4(0.f, 0.f, 0.f, 0.f);
    float4 acc2 = make_float4(0.f, 0.f, 0.f, 0.f);
    float4 acc3 = make_float4(0.f, 0.f, 0.f, 0.f);

    if (cnt <= 64) {
        int idx = (lane < cnt) ? (int)csr_src[base + lane] : 0;
        int j = 0;
        for (; j + 8 <= cnt; j += 8) {
            int s0 = __shfl(idx, j     + half);
            int s1 = __shfl(idx, j + 2 + half);
            int s2 = __shfl(idx, j + 4 + half);
            int s3 = __shfl(idx, j + 6 + half);
            g24(xh, xl, s0, col, acc0);
            g24(xh, xl, s1, col, acc1);
            g24(xh, xl, s2, col, acc2);
            g24(xh, xl, s3, col, acc3);
        }
        for (; j + 2 <= cnt; j += 2) {
            int s0 = __shfl(idx, j + half);
            g24(xh, xl, s0, col, acc0);
        }
        if (j < cnt) {
            int s0 = __shfl(idx, j);
            if (half == 0) g24(xh, xl, s0, col, acc1);
        }
    } else {
        int j = 0;
        for (; j + 2 <= cnt; j += 2) {
            int s = (int)csr_src[base + j + half];
            g24(xh, xl, s, col, acc0);
        }
        if (j < cnt && half == 0) {
            int s = (int)csr_src[base + j];
            g24(xh, xl, s, col, acc1);
        }
    }

    acc0.x += acc1.x + acc2.x + acc3.x;
    acc0.y += acc1.y + acc2.y + acc3.y;
    acc0.z += acc1.z + acc2.z + acc3.z;
    acc0.w += acc1.w + acc2.w + acc3.w;
    acc0.x += __shfl_down(acc0.x, 32);
    acc0.y += __shfl_down(acc0.y, 32);
    acc0.z += __shfl_down(acc0.z, 32);
    acc0.w += __shfl_down(acc0.w, 32);

    float4 r;
    r.x = fmaxf(di * (acc0.x + vs.x) + b.x, 0.f);
    r.y = fmaxf(di * (acc0.y + vs.y) + b.y, 0.f);
    r.z = fmaxf(di * (acc0.z + vs.z) + b.z, 0.f);
    r.w = fmaxf(di * (acc0.w + vs.w) + b.w, 0.f);

    if (fcw == nullptr) {
        if (half == 0)
            *reinterpret_cast<float4*>(outp + (size_t)node * D + col) = r;
    } else {
        float4 wv = *reinterpret_cast<const float4*>(fcw + col);
        float s = (half == 0) ? (r.x * wv.x + r.y * wv.y + r.z * wv.z + r.w * wv.w) : 0.f;
        #pragma unroll
        for (int off = 32; off > 0; off >>= 1) s += __shfl_down(s, off);
        if (lane == 0) fcout[node] = s + fcb[0];
    }
}

// ---------------- launch ----------------

extern "C" void kernel_launch(void* const* d_in, const int* in_sizes, int n_in,
                              void* d_out, int out_size, void* d_ws, size_t ws_size,
                              hipStream_t stream) {
    const float* x   = (const float*)d_in[0];
    const int*   ei  = (const int*)d_in[1];
    const float* W1  = (const float*)d_in[2];
    const float* b1  = (const float*)d_in[3];
    const float* W2  = (const float*)d_in[4];
    const float* b2  = (const float*)d_in[5];
    const float* W3  = (const float*)d_in[6];
    const float* b3  = (const float*)d_in[7];
    const float* Wfc = (const float*)d_in[8];
    const float* bfc = (const float*)d_in[9];
    float* outp = (float*)d_out;

    const int n = in_sizes[0] / D;        // 50000
    const int e = in_sizes[1] / 2;        // 800000
    const int* src = ei;
    const int* dst = ei + e;

    char* ws = (char*)d_ws;
    size_t off = 0;
    auto alloc = [&](size_t bytes) {
        void* p = ws + off;
        off += (bytes + 255) & ~(size_t)255;
        return p;
    };
    int*            deg     = (int*)alloc((size_t)n * 4);
    size_t          zero_bytes = off;     // deg zeroed
    int*            offsets = (int*)alloc((size_t)n * 4);
    float*          dinv    = (float*)alloc((size_t)n * 4);
    int*            blkSums = (int*)alloc(64 * 4);
    short*          Bsw     = (short*)alloc((size_t)3 * 32768 * 2);
    unsigned short* rank    = (unsigned short*)alloc((size_t)e * 2);
    unsigned short* csr_src = (unsigned short*)alloc((size_t)e * 2);
    unsigned short* xhbuf   = (unsigned short*)alloc((size_t)n * 128 * 2);  // fp24 hi16 [n][128]
    unsigned char*  xlbuf   = (unsigned char*)alloc((size_t)n * 128);       // fp24 lo8  [n][128]
    float*          buf1    = (float*)alloc((size_t)n * D * 4);             // fp32 h

    int eb256 = (e + 255) / 256;                           // 3125
    int scan_blocks = (n + SCAN_ELEMS - 1) / SCAN_ELEMS;   // 13 (<=64)
    int gemm_blocks = (n + 63) / 64;                       // 782
    int agg_blocks  = (n + 3) / 4;                         // 12500

    hipMemsetAsync(ws, 0, zero_bytes, stream);
    count_wsplit_kernel<<<eb256 + 192, 256, 0, stream>>>(dst, deg, rank, e, eb256,
                                                         W1, W2, W3, Bsw);
    scanA_kernel<<<scan_blocks, 256, 0, stream>>>(deg, blkSums, n);
    scanC_kernel<<<scan_blocks, 256, 0, stream>>>(deg, blkSums, offsets, dinv, n, scan_blocks);
    fill_gemm_kernel<<<eb256 + gemm_blocks, 256, 0, stream>>>(src, dst, offsets, rank, csr_src,
                                                              e, eb256, x, Bsw, dinv,
                                                              xhbuf, xlbuf, n);
    agg_kernel<<<agg_blocks, 256, 0, stream>>>(xhbuf, xlbuf, csr_src, offsets, deg, dinv, b1, buf1,
                                               nullptr, nullptr, nullptr, n);
    gemm_kernel<<<gemm_blocks, 256, 0, stream>>>(buf1, Bsw + 32768, dinv, xhbuf, xlbuf, n);
    agg_kernel<<<agg_blocks, 256, 0, stream>>>(xhbuf, xlbuf, csr_src, offsets, deg, dinv, b2, buf1,
                                               nullptr, nullptr, nullptr, n);
    gemm_kernel<<<gemm_blocks, 256, 0, stream>>>(buf1, Bsw + 65536, dinv, xhbuf, xlbuf, n);
    agg_kernel<<<agg_blocks, 256, 0, stream>>>(xhbuf, xlbuf, csr_src, offsets, deg, dinv, b3, nullptr,
                                               Wfc, bfc, outp, n);
}

// Round 13
// 327.779 us; speedup vs baseline: 1.8790x; 1.0253x over previous
//
#include <hip/hip_runtime.h>

#define D 128
#define SCAN_ELEMS 4096   // elements per scan block (256 threads x 16)

typedef __attribute__((ext_vector_type(8))) short short8;
typedef __attribute__((ext_vector_type(4))) float f32x4;

// ---------------- split-bf16 / fp24 helpers ----------------
__device__ inline void f2bf(float f, short& hi, short& lo) {
    union { float f; unsigned u; } a; a.f = f;
    unsigned r = a.u + 0x7fffu + ((a.u >> 16) & 1u);       // RNE to bf16
    hi = (short)(r >> 16);
    union { unsigned u; float f; } h; h.u = ((unsigned)(unsigned short)hi) << 16;
    union { float f; unsigned u; } b; b.f = f - h.f;
    unsigned r2 = b.u + 0x7fffu + ((b.u >> 16) & 1u);
    lo = (short)(r2 >> 16);
}

// fp24 encode: RNE-round fp32 to 24 bits (sign+8exp+15mant)
__device__ inline unsigned enc24(float f) {
    union { float f; unsigned u; } a; a.f = f;
    unsigned r = a.u + 0x7fu + ((a.u >> 8) & 1u);
    return r >> 8;
}

// decode 4 fp24 elems (row-major dual arrays) at row,col via v_perm_b32:
// elem = (hi<<16)|(lo<<8)  ->  one byte-permute per element.
__device__ inline void g24(const unsigned short* __restrict__ xh,
                           const unsigned char* __restrict__ xl,
                           int row, int c, float4& a) {
    unsigned off = ((unsigned)row << 7) + (unsigned)c;
    uint2 h2 = *reinterpret_cast<const uint2*>(xh + off);
    unsigned lb = *reinterpret_cast<const unsigned*>(xl + off);
    union { unsigned u; float f; } v0, v1, v2, v3;
    v0.u = __builtin_amdgcn_perm(h2.x, lb, 0x0504000Cu);  // {h.b1,h.b0,l.b0,0}
    v1.u = __builtin_amdgcn_perm(h2.x, lb, 0x0706010Cu);  // {h.b3,h.b2,l.b1,0}
    v2.u = __builtin_amdgcn_perm(h2.y, lb, 0x0504020Cu);  // {h.b1,h.b0,l.b2,0}
    v3.u = __builtin_amdgcn_perm(h2.y, lb, 0x0706030Cu);  // {h.b3,h.b2,l.b3,0}
    a.x += v0.f; a.y += v1.f; a.z += v2.f; a.w += v3.f;
}

// ---------------- precompute: count (+fused wsplit) ----------------
// deg[] counts REAL edges only (self-loop handled as +1 at use sites).

__device__ void wsplit_body(int tid, const float* __restrict__ W1,
                            const float* __restrict__ W2, const float* __restrict__ W3,
                            short* __restrict__ Bsw) {
    int layer = tid >> 14;
    int rem = tid & 16383;
    int k = rem >> 7, c = rem & 127;
    const float* Wg = (layer == 0) ? W1 : ((layer == 1) ? W2 : W3);
    float v = Wg[k * 128 + c];
    short hi, lo; f2bf(v, hi, lo);
    int ktile = k >> 5, kk = k & 31, q = kk >> 3, j = kk & 7;
    int ct = c >> 4, mm = c & 15, lane = q * 16 + mm;
    int idx = layer * 32768 + ((ktile * 8 + ct) * 64 + lane) * 8 + j;
    Bsw[idx] = hi;
    Bsw[idx + 16384] = lo;
}

__global__ __launch_bounds__(256) void count_wsplit_kernel(const int* __restrict__ dst,
                                                           int* __restrict__ deg,
                                                           unsigned short* __restrict__ rank,
                                                           int e, int nbCount,
                                                           const float* __restrict__ W1,
                                                           const float* __restrict__ W2,
                                                           const float* __restrict__ W3,
                                                           short* __restrict__ Bsw) {
    if ((int)blockIdx.x < nbCount) {
        int i = blockIdx.x * 256 + threadIdx.x;
        if (i < e) rank[i] = (unsigned short)atomicAdd(&deg[dst[i]], 1);
    } else {
        int tid = (blockIdx.x - nbCount) * 256 + threadIdx.x;
        wsplit_body(tid, W1, W2, W3, Bsw);
    }
}

// ---- hierarchical scan ----
__global__ __launch_bounds__(256) void scanA_kernel(const int* __restrict__ deg,
                                                    int* __restrict__ blkSums, int n) {
    __shared__ int waveSums[4];
    int t = threadIdx.x;
    int base = blockIdx.x * SCAN_ELEMS + t * 16;
    int s = 0;
    if (base + 16 <= n) {
        const int4* p = reinterpret_cast<const int4*>(deg + base);
        #pragma unroll
        for (int k = 0; k < 4; ++k) {
            int4 v = p[k];
            s += v.x + v.y + v.z + v.w;
        }
    } else {
        for (int k = 0; k < 16; ++k) {
            int i = base + k;
            if (i < n) s += deg[i];
        }
    }
    #pragma unroll
    for (int off = 32; off > 0; off >>= 1) s += __shfl_down(s, off);
    int lane = t & 63, w = t >> 6;
    if (lane == 0) waveSums[w] = s;
    __syncthreads();
    if (t == 0) blkSums[blockIdx.x] = waveSums[0] + waveSums[1] + waveSums[2] + waveSums[3];
}

__global__ __launch_bounds__(256) void scanC_kernel(const int* __restrict__ deg,
                                                    const int* __restrict__ blkSums,
                                                    int* __restrict__ offsets,
                                                    float* __restrict__ dinv, int n, int nblk) {
    __shared__ int waveSums[4];
    __shared__ int blkBase;
    int t = threadIdx.x;
    int lane = t & 63, w = t >> 6;

    if (t < 64) {
        int s = (t < nblk && t < (int)blockIdx.x) ? blkSums[t] : 0;
        #pragma unroll
        for (int off = 32; off > 0; off >>= 1) s += __shfl_down(s, off);
        if (t == 0) blkBase = s;
    }

    int base = blockIdx.x * SCAN_ELEMS + t * 16;
    int v[16];
    int s = 0;
    #pragma unroll
    for (int k = 0; k < 16; ++k) {
        int i = base + k;
        int d = (i < n) ? deg[i] : 0;
        v[k] = d;
        s += d;
    }
    int incl = s;
    #pragma unroll
    for (int off = 1; off < 64; off <<= 1) {
        int u = __shfl_up(incl, off);
        if (lane >= off) incl += u;
    }
    if (lane == 63) waveSums[w] = incl;
    __syncthreads();
    int waveOff = 0;
    for (int i = 0; i < 4; ++i) if (i < w) waveOff += waveSums[i];
    int off0 = blkBase + waveOff + incl - s;

    #pragma unroll
    for (int k = 0; k < 16; ++k) {
        int i = base + k;
        if (i < n) {
            offsets[i] = off0;
            dinv[i] = rsqrtf((float)(v[k] + 1));   // +1 self-loop
            off0 += v[k];
        }
    }
}

// ---------------- split-bf16 MFMA GEMM body (no LDS, row-major fp24 dual out) ----------------
__device__ void gemm_body(int blk, const float* __restrict__ A,
                          const short* __restrict__ Bsw,
                          const float* __restrict__ dinv,
                          unsigned short* __restrict__ xh,
                          unsigned char* __restrict__ xl, int n, int t) {
    int w = t >> 6;
    int lane = t & 63;
    int quad = lane >> 4;
    int m = lane & 15;

    int rowBase = blk * 64 + w * 16;
    int arow = rowBase + m;
    bool valid = arow < n;
    const float* ap = A + (size_t)(valid ? arow : 0) * D + quad * 8;

    f32x4 acc[8];
    #pragma unroll
    for (int ct = 0; ct < 8; ++ct) acc[ct] = (f32x4){0.f, 0.f, 0.f, 0.f};

    #pragma unroll
    for (int kt = 0; kt < 4; ++kt) {
        short8 a_hi, a_lo;
        {
            float4 f0 = *reinterpret_cast<const float4*>(ap + kt * 32);
            float4 f1 = *reinterpret_cast<const float4*>(ap + kt * 32 + 4);
            float fv[8] = {f0.x, f0.y, f0.z, f0.w, f1.x, f1.y, f1.z, f1.w};
            #pragma unroll
            for (int j = 0; j < 8; ++j) {
                short h, l; f2bf(valid ? fv[j] : 0.f, h, l);
                a_hi[j] = h; a_lo[j] = l;
            }
        }
        const short* bp = Bsw + (kt * 512 + lane) * 8;
        #pragma unroll
        for (int ct = 0; ct < 8; ++ct) {
            short8 b_hi = *reinterpret_cast<const short8*>(bp + ct * 512);
            short8 b_lo = *reinterpret_cast<const short8*>(bp + 16384 + ct * 512);
            acc[ct] = __builtin_amdgcn_mfma_f32_16x16x32_bf16(a_hi, b_hi, acc[ct], 0, 0, 0);
            acc[ct] = __builtin_amdgcn_mfma_f32_16x16x32_bf16(a_hi, b_lo, acc[ct], 0, 0, 0);
            acc[ct] = __builtin_amdgcn_mfma_f32_16x16x32_bf16(a_lo, b_hi, acc[ct], 0, 0, 0);
        }
    }

    // epilogue: C/D layout col=lane&15, row=quad*4+reg; row-major dual store
    #pragma unroll
    for (int r = 0; r < 4; ++r) {
        int row = rowBase + quad * 4 + r;
        if (row < n) {
            float s = dinv[row];
            size_t rb = (size_t)row * 128 + m;
            #pragma unroll
            for (int ct = 0; ct < 8; ++ct) {
                unsigned e24 = enc24(acc[ct][r] * s);
                xh[rb + ct * 16] = (unsigned short)(e24 >> 8);
                xl[rb + ct * 16] = (unsigned char)(e24 & 0xffu);
            }
        }
    }
}

__global__ __launch_bounds__(256) void gemm_kernel(const float* __restrict__ A,
                                                   const short* __restrict__ Bsw,
                                                   const float* __restrict__ dinv,
                                                   unsigned short* __restrict__ xh,
                                                   unsigned char* __restrict__ xl, int n) {
    gemm_body(blockIdx.x, A, Bsw, dinv, xh, xl, n, threadIdx.x);
}

// fill fused with layer-1 gemm (independent work, one dispatch)
__global__ __launch_bounds__(256) void fill_gemm_kernel(const int* __restrict__ src,
                                                        const int* __restrict__ dst,
                                                        const int* __restrict__ offsets,
                                                        const unsigned short* __restrict__ rank,
                                                        unsigned short* __restrict__ csr_src,
                                                        int e, int nbFill,
                                                        const float* __restrict__ A,
                                                        const short* __restrict__ Bsw,
                                                        const float* __restrict__ dinv,
                                                        unsigned short* __restrict__ xh,
                                                        unsigned char* __restrict__ xl, int n) {
    if ((int)blockIdx.x < nbFill) {
        int i = blockIdx.x * 256 + threadIdx.x;
        if (i < e) csr_src[offsets[dst[i]] + rank[i]] = (unsigned short)src[i];
    } else {
        gemm_body(blockIdx.x - nbFill, A, Bsw, dinv, xh, xl, n, threadIdx.x);
    }
}

// ---------------- aggregation (+ optional fused fc head) ----------------
// xws rows fp24 dual-array row-major, pre-scaled by dinv[row]:
//   h[d] = relu( dinv[d] * (sum_{e:s->d} xws[s] + xws[d]) + b )
__global__ __launch_bounds__(256) void agg_kernel(const unsigned short* __restrict__ xh,
                                                  const unsigned char* __restrict__ xl,
                                                  const unsigned short* __restrict__ csr_src,
                                                  const int* __restrict__ offsets,
                                                  const int* __restrict__ deg,
                                                  const float* __restrict__ dinv,
                                                  const float* __restrict__ bias,
                                                  float* __restrict__ outp,
                                                  const float* __restrict__ fcw,
                                                  const float* __restrict__ fcb,
                                                  float* __restrict__ fcout,
                                                  int n) {
    int wave = (blockIdx.x * blockDim.x + threadIdx.x) >> 6;
    int lane = threadIdx.x & 63;
    if (wave >= n) return;
    int node = wave;
    int half = lane >> 5;
    int l32  = lane & 31;
    int col  = l32 << 2;

    int base = offsets[node];
    int cnt  = deg[node];

    float di = dinv[node];
    float4 vs = make_float4(0.f, 0.f, 0.f, 0.f);
    g24(xh, xl, node, col, vs);
    float4 b = *reinterpret_cast<const float4*>(bias + col);

    float4 acc0 = make_float4(0.f, 0.f, 0.f, 0.f);
    float4 acc1 = make_float4(0.f, 0.f, 0.f, 0.f);
    float4 acc2 = make_float4(0.f, 0.f, 0.f, 0.f);
    float4 acc3 = make_float4(0.f, 0.f, 0.f, 0.f);

    if (cnt <= 64) {
        int idx = (lane < cnt) ? (int)csr_src[base + lane] : 0;
        int j = 0;
        for (; j + 8 <= cnt; j += 8) {
            int s0 = __shfl(idx, j     + half);
            int s1 = __shfl(idx, j + 2 + half);
            int s2 = __shfl(idx, j + 4 + half);
            int s3 = __shfl(idx, j + 6 + half);
            g24(xh, xl, s0, col, acc0);
            g24(xh, xl, s1, col, acc1);
            g24(xh, xl, s2, col, acc2);
            g24(xh, xl, s3, col, acc3);
        }
        for (; j + 2 <= cnt; j += 2) {
            int s0 = __shfl(idx, j + half);
            g24(xh, xl, s0, col, acc0);
        }
        if (j < cnt) {
            int s0 = __shfl(idx, j);
            if (half == 0) g24(xh, xl, s0, col, acc1);
        }
    } else {
        int j = 0;
        for (; j + 2 <= cnt; j += 2) {
            int s = (int)csr_src[base + j + half];
            g24(xh, xl, s, col, acc0);
        }
        if (j < cnt && half == 0) {
            int s = (int)csr_src[base + j];
            g24(xh, xl, s, col, acc1);
        }
    }

    acc0.x += acc1.x + acc2.x + acc3.x;
    acc0.y += acc1.y + acc2.y + acc3.y;
    acc0.z += acc1.z + acc2.z + acc3.z;
    acc0.w += acc1.w + acc2.w + acc3.w;
    acc0.x += __shfl_down(acc0.x, 32);
    acc0.y += __shfl_down(acc0.y, 32);
    acc0.z += __shfl_down(acc0.z, 32);
    acc0.w += __shfl_down(acc0.w, 32);

    float4 r;
    r.x = fmaxf(di * (acc0.x + vs.x) + b.x, 0.f);
    r.y = fmaxf(di * (acc0.y + vs.y) + b.y, 0.f);
    r.z = fmaxf(di * (acc0.z + vs.z) + b.z, 0.f);
    r.w = fmaxf(di * (acc0.w + vs.w) + b.w, 0.f);

    if (fcw == nullptr) {
        if (half == 0)
            *reinterpret_cast<float4*>(outp + (size_t)node * D + col) = r;
    } else {
        float4 wv = *reinterpret_cast<const float4*>(fcw + col);
        float s = (half == 0) ? (r.x * wv.x + r.y * wv.y + r.z * wv.z + r.w * wv.w) : 0.f;
        #pragma unroll
        for (int off = 32; off > 0; off >>= 1) s += __shfl_down(s, off);
        if (lane == 0) fcout[node] = s + fcb[0];
    }
}

// ---------------- launch ----------------

extern "C" void kernel_launch(void* const* d_in, const int* in_sizes, int n_in,
                              void* d_out, int out_size, void* d_ws, size_t ws_size,
                              hipStream_t stream) {
    const float* x   = (const float*)d_in[0];
    const int*   ei  = (const int*)d_in[1];
    const float* W1  = (const float*)d_in[2];
    const float* b1  = (const float*)d_in[3];
    const float* W2  = (const float*)d_in[4];
    const float* b2  = (const float*)d_in[5];
    const float* W3  = (const float*)d_in[6];
    const float* b3  = (const float*)d_in[7];
    const float* Wfc = (const float*)d_in[8];
    const float* bfc = (const float*)d_in[9];
    float* outp = (float*)d_out;

    const int n = in_sizes[0] / D;        // 50000
    const int e = in_sizes[1] / 2;        // 800000
    const int* src = ei;
    const int* dst = ei + e;

    char* ws = (char*)d_ws;
    size_t off = 0;
    auto alloc = [&](size_t bytes) {
        void* p = ws + off;
        off += (bytes + 255) & ~(size_t)255;
        return p;
    };
    int*            deg     = (int*)alloc((size_t)n * 4);
    size_t          zero_bytes = off;     // deg zeroed
    int*            offsets = (int*)alloc((size_t)n * 4);
    float*          dinv    = (float*)alloc((size_t)n * 4);
    int*            blkSums = (int*)alloc(64 * 4);
    short*          Bsw     = (short*)alloc((size_t)3 * 32768 * 2);
    unsigned short* rank    = (unsigned short*)alloc((size_t)e * 2);
    unsigned short* csr_src = (unsigned short*)alloc((size_t)e * 2);
    unsigned short* xhbuf   = (unsigned short*)alloc((size_t)n * 128 * 2);  // fp24 hi16 [n][128]
    unsigned char*  xlbuf   = (unsigned char*)alloc((size_t)n * 128);       // fp24 lo8  [n][128]
    float*          buf1    = (float*)alloc((size_t)n * D * 4);             // fp32 h

    int eb256 = (e + 255) / 256;                           // 3125
    int scan_blocks = (n + SCAN_ELEMS - 1) / SCAN_ELEMS;   // 13 (<=64)
    int gemm_blocks = (n + 63) / 64;                       // 782
    int agg_blocks  = (n + 3) / 4;                         // 12500

    hipMemsetAsync(ws, 0, zero_bytes, stream);
    count_wsplit_kernel<<<eb256 + 192, 256, 0, stream>>>(dst, deg, rank, e, eb256,
                                                         W1, W2, W3, Bsw);
    scanA_kernel<<<scan_blocks, 256, 0, stream>>>(deg, blkSums, n);
    scanC_kernel<<<scan_blocks, 256, 0, stream>>>(deg, blkSums, offsets, dinv, n, scan_blocks);
    fill_gemm_kernel<<<eb256 + gemm_blocks, 256, 0, stream>>>(src, dst, offsets, rank, csr_src,
                                                              e, eb256, x, Bsw, dinv,
                                                              xhbuf, xlbuf, n);
    agg_kernel<<<agg_blocks, 256, 0, stream>>>(xhbuf, xlbuf, csr_src, offsets, deg, dinv, b1, buf1,
                                               nullptr, nullptr, nullptr, n);
    gemm_kernel<<<gemm_blocks, 256, 0, stream>>>(buf1, Bsw + 32768, dinv, xhbuf, xlbuf, n);
    agg_kernel<<<agg_blocks, 256, 0, stream>>>(xhbuf, xlbuf, csr_src, offsets, deg, dinv, b2, buf1,
                                               nullptr, nullptr, nullptr, n);
    gemm_kernel<<<gemm_blocks, 256, 0, stream>>>(buf1, Bsw + 65536, dinv, xhbuf, xlbuf, n);
    agg_kernel<<<agg_blocks, 256, 0, stream>>>(xhbuf, xlbuf, csr_src, offsets, deg, dinv, b3, nullptr,
                                               Wfc, bfc, outp, n);
}